// Round 2
// baseline (1826.155 us; speedup 1.0000x reference)
//
#include <hip/hip_runtime.h>
#include <hip/hip_bf16.h>

#define SEQ   128
#define BATCH 48
#define VOCAB 50257
#define EMB   32
#define HID   8
#define H2    16
#define ROWS  (SEQ*BATCH)        // 6144
#define LOG2E 1.4426950408889634f
#define SHIFT 30.0f

// vocab pass tiling
#define CPT 4                    // columns per thread (h2o kept in 64 VGPRs)
#define TPB 256
#define CPB (CPT*TPB)            // 1024 columns per block
#define NVB 50                   // ceil(VOCAB/CPB)
#define TGR 16                   // row-groups over t
#define TR  (SEQ/TGR)            // 8 t's per block

// ws layout (floats):
//  X    @ 0       : SEQ*BATCH*HID = 49152   (emb @ We, shared fwd/bwd)
//  hcat @ 49152   : ROWS*16       = 98304   ([hf_used | hb_used])
//  S    @ 147456  : ROWS          = 6144    (partial sum-exp, atomics)
//  c    @ 153600  : ROWS          = 6144    (30 + ln S)
// total 159744 floats = 624 KB

// ---------------- K0: embedding gather + X = emb @ We; zero S ----------------
__global__ void __launch_bounds__(256) k0_embed(
    const int* __restrict__ ids, const float* __restrict__ we,
    const float* __restrict__ i2h, float* __restrict__ X,
    float* __restrict__ S) {
  __shared__ float w[EMB*HID];
  int tid = threadIdx.x;
  if (tid < EMB*HID) w[tid] = i2h[tid];
  __syncthreads();
  int n = blockIdx.x*256 + tid;          // n = t*BATCH + b, grid covers ROWS
  if (n >= ROWS) return;
  S[n] = 0.0f;                           // re-zero every call (ws is poisoned)
  int id = ids[n];
  const float* er = we + (size_t)id*EMB; // we rows are 128B aligned
  float e[EMB];
  #pragma unroll
  for (int k4 = 0; k4 < EMB/4; k4++) {
    float4 v = ((const float4*)er)[k4];
    e[4*k4+0]=v.x; e[4*k4+1]=v.y; e[4*k4+2]=v.z; e[4*k4+3]=v.w;
  }
  #pragma unroll
  for (int j = 0; j < HID; j++) {
    float acc = 0.f;
    #pragma unroll
    for (int k = 0; k < EMB; k++) acc += e[k]*w[k*HID+j];
    X[(size_t)n*HID + j] = acc;
  }
}

// ---------------- K1: sequential bi-RNN scan, LDS-resident ----------------
// 12 blocks x 64 threads: block = (dir, batch-group of 8). thread = (b', j).
// hcat[t][b][0:8] = h before token t (forward); hcat[t][b][8:16] = h before
// token t (backward, i.e. state after tokens SEQ-1..t+1).
__device__ __forceinline__ float tanh_fast(float x) {
  float ex = __builtin_amdgcn_exp2f(x * (2.0f*LOG2E));
  return 1.0f - 2.0f/(ex + 1.0f);
}

__global__ void __launch_bounds__(64) k1_rnn(
    const float* __restrict__ X, const float* __restrict__ i2h,
    const float* __restrict__ h0f, const float* __restrict__ h0b,
    float* __restrict__ hcat) {
  __shared__ float xs[SEQ*64];           // 32 KB: xs[t*64 + b'*8 + j]
  __shared__ float hs[64];
  int tid = threadIdx.x;
  int dir = blockIdx.x / 6;              // 0 = fwd, 1 = bwd
  int bg  = blockIdx.x % 6;
  int bl = tid >> 3, j = tid & 7;
  int b = bg*8 + bl;
  // preload this block's X slice (contiguous 64 floats per t)
  for (int i = tid; i < SEQ*64; i += 64) {
    int t = i >> 6, o = i & 63;
    xs[i] = X[(size_t)(t*BATCH + bg*8)*HID + o];
  }
  float wh[HID];
  #pragma unroll
  for (int k = 0; k < HID; k++) wh[k] = i2h[(EMB+k)*HID + j];
  float h = dir ? h0b[b*HID+j] : h0f[b*HID+j];
  __syncthreads();
  for (int s = 0; s < SEQ; s++) {
    int t = dir ? (SEQ-1-s) : s;
    hcat[(size_t)(t*BATCH+b)*H2 + dir*HID + j] = h;   // state BEFORE token t
    hs[tid] = h;
    __syncthreads();
    float acc = xs[t*64 + bl*8 + j];
    #pragma unroll
    for (int k = 0; k < HID; k++) acc += hs[bl*8+k]*wh[k];
    h = tanh_fast(acc);
    __syncthreads();
  }
}

// ---------------- K2a: pass 1 — partial sum-exp per row ----------------
// Thread handles 4 strided columns v = vblk*CPB + i*TPB + tid so every h2o
// load is a coalesced 64x4B wave transaction. h2o stays in 64 VGPRs for the
// whole kernel; rows stream (b outer for bias reuse, t inner). Per row:
// 64 FMA + 4 exp2 + wave butterfly + one fp32 atomicAdd per wave.
__global__ void __launch_bounds__(256) k2a_stats(
    const float* __restrict__ h2o, const float* __restrict__ bias,
    const float* __restrict__ hcat, float* __restrict__ S) {
  int vblk = blockIdx.x % NVB;
  int tg   = blockIdx.x / NVB;
  int tid  = threadIdx.x;
  int vb   = vblk*CPB + tid;
  float w[H2][CPT], msk[CPT];
  #pragma unroll
  for (int i = 0; i < CPT; i++) msk[i] = (vb + i*TPB < VOCAB) ? 1.f : 0.f;
  #pragma unroll
  for (int k = 0; k < H2; k++)
    #pragma unroll
    for (int i = 0; i < CPT; i++)
      w[k][i] = (vb + i*TPB < VOCAB) ? h2o[(size_t)k*VOCAB + vb + i*TPB] : 0.f;
  for (int b = 0; b < BATCH; b++) {
    float bb[CPT];
    #pragma unroll
    for (int i = 0; i < CPT; i++)
      bb[i] = (vb + i*TPB < VOCAB) ? bias[(size_t)b*VOCAB + vb + i*TPB] : 0.f;
    for (int tt = 0; tt < TR; tt++) {
      int r = (tg*TR+tt)*BATCH + b;
      const float* hr = hcat + (size_t)r*H2;   // uniform -> s_load
      float l[CPT] = {bb[0],bb[1],bb[2],bb[3]};
      #pragma unroll
      for (int k = 0; k < H2; k++) {
        float hk = hr[k];
        #pragma unroll
        for (int i = 0; i < CPT; i++) l[i] += hk*w[k][i];
      }
      float s = 0.f;
      #pragma unroll
      for (int i = 0; i < CPT; i++)
        s += msk[i]*__builtin_amdgcn_exp2f((l[i]-SHIFT)*LOG2E);
      #pragma unroll
      for (int off = 32; off >= 1; off >>= 1) s += __shfl_xor(s, off, 64);
      if ((tid & 63) == 0) atomicAdd(S + r, s);
    }
  }
}

// ---------------- K2b: c[r] = SHIFT + ln(S[r]) ----------------
// (v_log_f32 is log2; multiply by ln2 to get natural log)
__global__ void __launch_bounds__(256) k2b_logs(
    const float* __restrict__ S, float* __restrict__ c) {
  int r = blockIdx.x*256 + threadIdx.x;
  if (r < ROWS) c[r] = SHIFT + __builtin_amdgcn_logf(S[r]) * (1.0f/LOG2E);
}

// ---------------- K2c: pass 2 — recompute logits, write fp32 ----------------
__global__ void __launch_bounds__(256) k2c_write(
    const float* __restrict__ h2o, const float* __restrict__ bias,
    const float* __restrict__ hcat, const float* __restrict__ c,
    float* __restrict__ out) {
  int vblk = blockIdx.x % NVB;
  int tg   = blockIdx.x / NVB;
  int tid  = threadIdx.x;
  int vb   = vblk*CPB + tid;
  float w[H2][CPT];
  #pragma unroll
  for (int k = 0; k < H2; k++)
    #pragma unroll
    for (int i = 0; i < CPT; i++)
      w[k][i] = (vb + i*TPB < VOCAB) ? h2o[(size_t)k*VOCAB + vb + i*TPB] : 0.f;
  for (int b = 0; b < BATCH; b++) {
    float bb[CPT];
    #pragma unroll
    for (int i = 0; i < CPT; i++)
      bb[i] = (vb + i*TPB < VOCAB) ? bias[(size_t)b*VOCAB + vb + i*TPB] : 0.f;
    for (int tt = 0; tt < TR; tt++) {
      int r = (tg*TR+tt)*BATCH + b;
      const float* hr = hcat + (size_t)r*H2;
      float cr = c[r];
      float l[CPT] = {bb[0],bb[1],bb[2],bb[3]};
      #pragma unroll
      for (int k = 0; k < H2; k++) {
        float hk = hr[k];
        #pragma unroll
        for (int i = 0; i < CPT; i++) l[i] += hk*w[k][i];
      }
      size_t base = (size_t)r*VOCAB + vb;
      #pragma unroll
      for (int i = 0; i < CPT; i++)
        if (vb + i*TPB < VOCAB) out[base + i*TPB] = l[i] - cr;
    }
  }
}

extern "C" void kernel_launch(void* const* d_in, const int* in_sizes, int n_in,
                              void* d_out, int out_size, void* d_ws, size_t ws_size,
                              hipStream_t stream) {
  const int*   ids  = (const int*)d_in[0];
  const float* we   = (const float*)d_in[1];
  const float* i2h  = (const float*)d_in[2];
  const float* h2o  = (const float*)d_in[3];
  const float* bias = (const float*)d_in[4];
  const float* h0f  = (const float*)d_in[5];
  const float* h0b  = (const float*)d_in[6];
  float* ws   = (float*)d_ws;
  float* X    = ws;
  float* hcat = ws + 49152;
  float* S    = ws + 147456;
  float* c    = ws + 153600;
  float* out  = (float*)d_out;

  k0_embed<<<ROWS/256, 256, 0, stream>>>(ids, we, i2h, X, S);
  k1_rnn  <<<12, 64, 0, stream>>>(X, i2h, h0f, h0b, hcat);
  k2a_stats<<<NVB*TGR, 256, 0, stream>>>(h2o, bias, hcat, S);
  k2b_logs<<<ROWS/256, 256, 0, stream>>>(S, c);
  k2c_write<<<NVB*TGR, 256, 0, stream>>>(h2o, bias, hcat, c, out);
}